// Round 11
// baseline (384.304 us; speedup 1.0000x reference)
//
#include <hip/hip_runtime.h>
#include <float.h>

// SearchTransfer MI355X — R11: GEMM tile 256²->128² (256 thr, 4 waves) with
// 2 blocks/CU: trades 2x staging traffic for 2x DMA concurrency (m97/m114:
// cross-block wave overlap fills the barrier vmcnt drain; 21.8 B/cyc/CU at
// 3 blocks/CU vs our measured 9.9 at 1). k_pack2/foldmerge logic unchanged
// (NRT 36->72). Split-f16 3-term GEMM (K'=320), tau=2^-6 guard, exact fixup.
// B=2, C=16, H=W=96, k=3,pad=1,stride=1, lv=2. L=9216, KF=144.
// out = [T_org (2*16*192*192 f32), S (2*9216 as f32)]

#define BATCH 2
#define CCH   16
#define HH    96
#define WW    96
#define LP    9216
#define KF    144
#define K3    320      // 5 chunks x 64 k' ; chunk = [hi32|lo32] of k-slice
#define OH    192
#define OW    192
#define NRT3  72       // row tiles of 128
#define NCB3  72       // col blocks of 128

typedef _Float16 f16;
typedef __attribute__((ext_vector_type(8))) _Float16 f16x8;
typedef __attribute__((ext_vector_type(4))) float    f32x4;

__device__ __forceinline__ void async16(const void* g, void* l) {
    __builtin_amdgcn_global_load_lds(
        (const __attribute__((address_space(1))) void*)g,
        (__attribute__((address_space(3))) void*)l, 16, 0, 0);
}

// ---------------------------------------------------- fused norm + pack ----
// UNCHANGED from R9/R10. Block = (py, batch, side*4+quarter). Norms
// bit-identical (zero-padded terms exact); 24 rows x 40 granules; layout:
// granule g: slice=g>>3, half=(g>>2)&1, j=g&3.
__global__ __launch_bounds__(256) void k_pack2(
        const float* __restrict__ ref, const float* __restrict__ lr,
        float* __restrict__ rinv, float* __restrict__ bns,
        f16* __restrict__ Abig, f16* __restrict__ Bbig) {
    __shared__ float imgS[CCH][3][26];   // x origin at global xi = q*24-1
    __shared__ float scl[24];
    int py = blockIdx.x, b = blockIdx.y;
    int side = blockIdx.z >> 2, q = blockIdx.z & 3;
    int tid = threadIdx.x;
    const float* img = (side ? lr : ref) + (size_t)b * CCH * HH * WW;

    for (int i = tid; i < CCH * 3 * 26; i += 256) {
        int c = i / 78, rem = i - c * 78;
        int rr = rem / 26, xx = rem - rr * 26;
        int y = py + rr - 1, xi = q * 24 - 1 + xx;
        float v = 0.f;
        if ((unsigned)y < (unsigned)HH && (unsigned)xi < (unsigned)WW)
            v = img[(c * HH + y) * WW + xi];
        imgS[c][rr][xx] = v;
    }
    __syncthreads();

    if (tid < 24) {
        int pxl = tid;
        float s = 0.f;
        for (int c = 0; c < CCH; ++c)
            #pragma unroll
            for (int dy = 0; dy < 3; ++dy)
                #pragma unroll
                for (int dx = 0; dx < 3; ++dx) {
                    float v = imgS[c][dy][pxl + dx];   // 0 when OOB: exact
                    s += v * v;
                }
        int gl = b * LP + py * 96 + q * 24 + pxl;
        if (side) { bns[gl] = 1024.0f * sqrtf(s); scl[pxl] = 1024.0f; }
        else { float r = 1.0f / fmaxf(sqrtf(s), 1e-12f); rinv[gl] = r; scl[pxl] = 1024.0f * r; }
    }
    __syncthreads();

    f16* dstb = (side ? Bbig : Abig) + (size_t)(b * LP + py * 96 + q * 24) * K3;
    for (int i = tid; i < 24 * 40; i += 256) {          // 40 granules/row
        int pxl = i / 40, g = i - pxl * 40;
        int chunk = g >> 3, half = (g >> 2) & 1, j = g & 3;
        int f0 = chunk * 32 + j * 8;                    // original k base
        float sc = scl[pxl];
        f16x8 o;
        #pragma unroll
        for (int e = 0; e < 8; ++e) {
            int f = f0 + e;                             // 0..159 (>=144 pad)
            float v = 0.f;
            if (f < KF) {
                int c = f / 9, r9 = f - c * 9;
                int dy = r9 / 3, dx = r9 - dy * 3;
                v = imgS[c][dy][pxl + dx] * sc;
            }
            f16 h = (f16)v;
            o[e] = half ? (f16)(v - (float)h) : h;
        }
        *(f16x8*)(dstb + (size_t)pxl * K3 + g * 8) = o;
    }
}

// -------------------------------------------------- MFMA GEMM + top-2 ------
// 128x128 block, 256 threads = 4 waves (2x2 of 64x64 micro-tiles), 5 chunks
// of 64 k' (32 KB), double-buffered (64 KB LDS total -> 2 blocks/CU),
// post-barrier prefetch, XCD swizzle (18 (b,rt) per XCD, col-major sweep).
// Per chunk: 3 pairings hi*hi, hi*lo, lo*hi from ks=0/1 frags.
__global__ __launch_bounds__(256) void k_mfma(
        const f16* __restrict__ Abig, const f16* __restrict__ Bbig,
        float* __restrict__ pv1, int* __restrict__ pi1, float* __restrict__ pv2) {
    __shared__ f16 smem[2][256 * 64];                  // 2 x 32 KB; rows 0-127=A, 128-255=B
    int tid = threadIdx.x, lane = tid & 63, w = tid >> 6;   // w: 0..3
    int wm = w & 1, wn = w >> 1;
    int l15 = lane & 15, quad = lane >> 4, l7 = lane & 7;

    int i = blockIdx.x;                // 0..10367
    int xcd = i & 7, slot = i >> 3;    // slot 0..1295
    int cb = slot / 18;                // col tile 0..71 (major)
    int brt = xcd * 18 + (slot - cb * 18);   // 0..143
    int b = brt / NRT3, rt = brt - b * NRT3;
    int r0 = rt * 128, c0 = cb * 128;

    // staging: 32 groups of 8 rows; wave w owns groups w*8..w*8+7.
    int srow = lane >> 3;              // row within group
    int sg   = (lane & 7) ^ srow;      // source granule (self-inverse swizzle)
    const f16* gsrc[8];
    int ldsbyte[8];                    // wave-uniform byte offset in one buffer
    #pragma unroll
    for (int j = 0; j < 8; ++j) {
        int G = w * 8 + j;             // 0..31
        int row8 = G * 8 + srow;       // 0..255 (A rows then B rows)
        const f16* base = (row8 < 128)
            ? Abig + (size_t)(b * LP + r0 + row8) * K3
            : Bbig + (size_t)(b * LP + c0 + (row8 - 128)) * K3;
        gsrc[j] = base + sg * 8;
        ldsbyte[j] = G * 1024;         // G*8 rows * 128 B/row
    }
    int arow[4], brow[4];              // frag row byte offsets (row stride 128 B)
    #pragma unroll
    for (int t = 0; t < 4; ++t) {
        arow[t] = (wm * 64 + t * 16 + l15) * 128;
        brow[t] = (128 + wn * 64 + t * 16 + l15) * 128;
    }

    f32x4 acc[4][4];
    #pragma unroll
    for (int ii = 0; ii < 4; ++ii)
        #pragma unroll
        for (int j = 0; j < 4; ++j) { acc[ii][j][0]=0.f; acc[ii][j][1]=0.f; acc[ii][j][2]=0.f; acc[ii][j][3]=0.f; }

    // prologue: chunk 0 -> buf 0
    #pragma unroll
    for (int j = 0; j < 8; ++j) async16(gsrc[j], (char*)smem[0] + ldsbyte[j]);

    for (int ch = 0; ch < 5; ++ch) {
        __syncthreads();               // drains own DMA; buf[ch&1] ready
        if (ch < 4) {
            #pragma unroll
            for (int j = 0; j < 8; ++j)
                async16(gsrc[j] + (ch + 1) * 64, (char*)smem[(ch + 1) & 1] + ldsbyte[j]);
        }
        const char* buf = (const char*)smem[ch & 1];
        int ph0 = ((quad) ^ l7) << 4;          // hi granules 0-3
        int ph1 = ((4 + quad) ^ l7) << 4;      // lo granules 4-7
        f16x8 af0[4], bf0[4], bf1[4], af1[4];
        // phase 1: hi*hi
        #pragma unroll
        for (int t = 0; t < 4; ++t) af0[t] = *(const f16x8*)(buf + arow[t] + ph0);
        #pragma unroll
        for (int t = 0; t < 4; ++t) bf0[t] = *(const f16x8*)(buf + brow[t] + ph0);
        #pragma unroll
        for (int rtt = 0; rtt < 4; ++rtt)
            #pragma unroll
            for (int ct = 0; ct < 4; ++ct)
                acc[rtt][ct] = __builtin_amdgcn_mfma_f32_16x16x32_f16(af0[rtt], bf0[ct], acc[rtt][ct], 0, 0, 0);
        // phase 2: hi*lo
        #pragma unroll
        for (int t = 0; t < 4; ++t) bf1[t] = *(const f16x8*)(buf + brow[t] + ph1);
        #pragma unroll
        for (int rtt = 0; rtt < 4; ++rtt)
            #pragma unroll
            for (int ct = 0; ct < 4; ++ct)
                acc[rtt][ct] = __builtin_amdgcn_mfma_f32_16x16x32_f16(af0[rtt], bf1[ct], acc[rtt][ct], 0, 0, 0);
        // phase 3: lo*hi
        #pragma unroll
        for (int t = 0; t < 4; ++t) af1[t] = *(const f16x8*)(buf + arow[t] + ph1);
        #pragma unroll
        for (int rtt = 0; rtt < 4; ++rtt)
            #pragma unroll
            for (int ct = 0; ct < 4; ++ct)
                acc[rtt][ct] = __builtin_amdgcn_mfma_f32_16x16x32_f16(af1[rtt], bf0[ct], acc[rtt][ct], 0, 0, 0);
    }
    __syncthreads();                   // smem reads done -> overlay epilogue scratch

    float* sv1 = (float*)smem;                         // [2][128]
    int*   si1 = (int*)  ((char*)smem + 1024);
    float* sv2 = (float*)((char*)smem + 2048);

    int rbase = r0 + wm * 64 + (quad << 2);
    #pragma unroll
    for (int ct = 0; ct < 4; ++ct) {
        float v1 = -FLT_MAX, v2 = -FLT_MAX; int i1 = 0;
        #pragma unroll
        for (int rtt = 0; rtt < 4; ++rtt)
            #pragma unroll
            for (int e = 0; e < 4; ++e) {              // ascending rows; strict > = first wins
                float v = acc[rtt][ct][e];
                int rg = rbase + rtt * 16 + e;
                if (v > v1) { v2 = v1; v1 = v; i1 = rg; }
                else if (v > v2) v2 = v;
            }
        #pragma unroll
        for (int off = 16; off < 64; off <<= 1) {      // reduce over quad (rows)
            float ov1 = __shfl_xor(v1, off, 64);
            int   oi1 = __shfl_xor(i1, off, 64);
            float ov2 = __shfl_xor(v2, off, 64);
            if (ov1 > v1 || (ov1 == v1 && oi1 < i1)) { v2 = fmaxf(v1, ov2); v1 = ov1; i1 = oi1; }
            else v2 = fmaxf(v2, ov1);
        }
        if (quad == 0) {
            int col = wn * 64 + ct * 16 + l15;         // 0..127
            sv1[wm * 128 + col] = v1; si1[wm * 128 + col] = i1; sv2[wm * 128 + col] = v2;
        }
    }
    __syncthreads();
    if (tid < 128) {
        int col = tid;
        float v1 = sv1[col]; int i1 = si1[col]; float v2 = sv2[col];
        float ov1 = sv1[128 + col]; int oi1 = si1[128 + col]; float ov2 = sv2[128 + col];
        if (ov1 > v1) { v2 = fmaxf(v1, ov2); v1 = ov1; i1 = oi1; }   // wm1 rows > wm0: ties keep wm0
        else v2 = fmaxf(v2, ov1);
        size_t o = ((size_t)(b * NRT3 + rt)) * LP + c0 + col;
        pv1[o] = v1; pi1[o] = i1; pv2[o] = v2;
    }
}

// -------------------------------------- fused merge + fixup + fold ---------
// Block = (b, 16x16 pixel tile). Phase A: merge <=10x10 patch neighborhood
// over 72 row-chunks (ascending rc = first-wins; flag iff gap < bns*2^-6);
// owner patches write Sout. Phase B: pruned exact fp32 argmax for flagged
// patches (rare; duplicated across neighbor blocks, idempotent; rows
// rc*128+(tid&127), upper half duplicates — harmless for argmax). Phase C:
// fold with S from LDS, 9-patch base reused across 16 channels.
__global__ __launch_bounds__(256) void k_foldmerge(
        const float* __restrict__ refimg, const float* __restrict__ lrimg,
        const float* __restrict__ rinv,
        const float* __restrict__ pv1, const int* __restrict__ pi1,
        const float* __restrict__ pv2, const float* __restrict__ bns,
        const float* __restrict__ org,
        float* __restrict__ outT, float* __restrict__ Sout) {
    __shared__ int   s_S[10][10];
    __shared__ int   s_flag[100];
    __shared__ int   s_nflag;
    __shared__ float bcol[KF];
    __shared__ float spv[NRT3];
    __shared__ float red[4]; __shared__ int redi[4];
    int tx = blockIdx.x, ty = blockIdx.y, b = blockIdx.z;
    int x0 = tx * 16, y0 = ty * 16;
    int lhb = 8 * ty - 1; if (lhb < 0) lhb = 0;
    int lwb = 8 * tx - 1; if (lwb < 0) lwb = 0;
    int lhe = 8 * ty + 8; if (lhe > 95) lhe = 95;
    int lwe = 8 * tx + 8; if (lwe > 95) lwe = 95;
    int tid = threadIdx.x;

    if (tid == 0) s_nflag = 0;
    __syncthreads();

    // ---- Phase A: merge ----
    if (tid < 100) {
        int ph = tid / 10, pw = tid - ph * 10;
        int lh = lhb + ph, lw = lwb + pw;
        if (lh <= lhe && lw <= lwe) {
            int col = lh * 96 + lw;
            float v1 = -FLT_MAX, v2 = -FLT_MAX; int i1 = 0;
            for (int rc = 0; rc < NRT3; ++rc) {        // ascending: first-wins
                size_t o = ((size_t)(b * NRT3 + rc)) * LP + col;
                float cv1 = pv1[o]; int ci1 = pi1[o]; float cv2 = pv2[o];
                if (cv1 > v1) { v2 = fmaxf(v1, cv2); v1 = cv1; i1 = ci1; }
                else v2 = fmaxf(v2, cv1);
            }
            s_S[ph][pw] = i1;
            float tau = bns[b * LP + col] * 0.015625f; // 2^-6
            if (v1 - v2 < tau) { int k = atomicAdd(&s_nflag, 1); s_flag[k] = tid; }
            if (lh >= 8 * ty && lh < 8 * ty + 8 && lw >= 8 * tx && lw < 8 * tx + 8)
                Sout[b * LP + col] = (float)i1;        // owner write (partition)
        }
    }
    __syncthreads();

    // ---- Phase B: exact fixup for flagged patches (rare) ----
    int nf = s_nflag;
    for (int fi = 0; fi < nf; ++fi) {
        int pt = s_flag[fi];
        int ph = pt / 10, pw = pt - ph * 10;
        int lh = lhb + ph, lw = lwb + pw;
        int col = lh * 96 + lw, gid = b * LP + col;
        __syncthreads();                               // protect bcol/spv reuse
        if (tid < KF) {
            int c = tid / 9, r = tid - c * 9;
            int dy = r / 3, dx = r - dy * 3;
            int y = lh + dy - 1, x = lw + dx - 1;
            float v = 0.f;
            if ((unsigned)y < (unsigned)HH && (unsigned)x < (unsigned)WW)
                v = lrimg[((size_t)(b * CCH + c) * HH + y) * WW + x];
            bcol[tid] = v;
        }
        if (tid < NRT3) spv[tid] = pv1[((size_t)(b * NRT3 + tid)) * LP + col];
        __syncthreads();
        float v1 = -FLT_MAX;
        for (int rc = 0; rc < NRT3; ++rc) v1 = fmaxf(v1, spv[rc]);
        float thresh = v1 - bns[gid] * 0.015625f;
        float best = -FLT_MAX; int bi = 0x7fffffff;
        for (int rc = 0; rc < NRT3; ++rc) {            // ascending rows
            if (spv[rc] < thresh) continue;            // prune (uniform)
            int row = rc * 128 + (tid & 127);          // upper half duplicates
            int py = row / WW, px = row - py * WW;
            float s = 0.f;
            for (int c = 0; c < CCH; ++c) {
                const float* ic = refimg + (size_t)(b * CCH + c) * HH * WW;
                #pragma unroll
                for (int dy = 0; dy < 3; ++dy) {
                    int y = py + dy - 1;
                    if ((unsigned)y >= (unsigned)HH) continue;
                    #pragma unroll
                    for (int dx = 0; dx < 3; ++dx) {
                        int x = px + dx - 1;
                        if ((unsigned)x >= (unsigned)WW) continue;
                        s = fmaf(ic[y * WW + x], bcol[c * 9 + dy * 3 + dx], s);
                    }
                }
            }
            s *= rinv[b * LP + row];
            if (s > best || (s == best && row < bi)) { best = s; bi = row; }
        }
        #pragma unroll
        for (int off = 1; off < 64; off <<= 1) {
            float ov = __shfl_xor(best, off, 64);
            int   oi = __shfl_xor(bi, off, 64);
            if (ov > best || (ov == best && oi < bi)) { best = ov; bi = oi; }
        }
        if ((tid & 63) == 0) { red[tid >> 6] = best; redi[tid >> 6] = bi; }
        __syncthreads();
        if (tid == 0) {
            float b0 = red[0]; int i0 = redi[0];
            for (int k = 1; k < 4; ++k)
                if (red[k] > b0 || (red[k] == b0 && redi[k] < i0)) { b0 = red[k]; i0 = redi[k]; }
            s_S[ph][pw] = i0;
            if (lh >= 8 * ty && lh < 8 * ty + 8 && lw >= 8 * tx && lw < 8 * tx + 8)
                Sout[gid] = (float)i0;
        }
    }
    __syncthreads();

    // ---- Phase C: fold (per pixel, all 16 channels) ----
    int pyL = tid >> 4, pxL = tid & 15;
    int y = y0 + pyL, x = x0 + pxL;
    const float* orgb = org + (size_t)b * CCH * OH * OW;
    float acc[CCH];
    #pragma unroll
    for (int c = 0; c < CCH; ++c) acc[c] = 0.f;
    int lhm = (y + 2) >> 1;
    int lwm = (x + 2) >> 1;
    int lh0 = lhm - 2 > 0 ? lhm - 2 : 0;
    int lh1 = lhm < 95 ? lhm : 95;
    int lw0 = lwm - 2 > 0 ? lwm - 2 : 0;
    int lw1 = lwm < 95 ? lwm : 95;
    for (int lh = lh0; lh <= lh1; ++lh) {
        int dy = y + 2 - 2 * lh;
        if (dy > 5) continue;
        for (int lw = lw0; lw <= lw1; ++lw) {
            int dx = x + 2 - 2 * lw;
            if (dx > 5) continue;
            int s  = s_S[lh - lhb][lw - lwb];
            int sh = s / 96, sw = s - sh * 96;
            int u = 2 * sh + dy - 2;
            int v = 2 * sw + dx - 2;
            if ((unsigned)u < (unsigned)OH && (unsigned)v < (unsigned)OW) {
                const float* p = orgb + u * OW + v;
                #pragma unroll
                for (int c = 0; c < CCH; ++c) acc[c] += p[(size_t)c * OH * OW];
            }
        }
    }
    #pragma unroll
    for (int c = 0; c < CCH; ++c)
        outT[(((size_t)(b * CCH + c)) * OH + y) * OW + x] = acc[c];
}

// --------------------------------------------------------------- launch ----
extern "C" void kernel_launch(void* const* d_in, const int* in_sizes, int n_in,
                              void* d_out, int out_size, void* d_ws, size_t ws_size,
                              hipStream_t stream) {
    const float* lrsr  = (const float*)d_in[0];
    const float* refsr = (const float*)d_in[1];
    const float* org   = (const float*)d_in[2];

    char* ws = (char*)d_ws;
    size_t o = 0;
    float* rinv     = (float*)(ws + o); o += (size_t)BATCH * LP * 4;
    float* bns      = (float*)(ws + o); o += (size_t)BATCH * LP * 4;
    float* pv1      = (float*)(ws + o); o += (size_t)BATCH * NRT3 * LP * 4;
    int*   pi1      = (int*)  (ws + o); o += (size_t)BATCH * NRT3 * LP * 4;
    float* pv2      = (float*)(ws + o); o += (size_t)BATCH * NRT3 * LP * 4;
    f16*   Abig     = (f16*)  (ws + o); o += (size_t)BATCH * LP * K3 * 2;
    f16*   Bbig     = (f16*)  (ws + o); o += (size_t)BATCH * LP * K3 * 2;

    float* outT = (float*)d_out;                          // 2*16*192*192
    float* outS = outT + (size_t)BATCH * CCH * OH * OW;   // 2*9216 as f32

    k_pack2<<<dim3(96, BATCH, 8), 256, 0, stream>>>(refsr, lrsr, rinv, bns, Abig, Bbig);
    k_mfma<<<dim3(NCB3 * NRT3 * BATCH), 256, 0, stream>>>(Abig, Bbig, pv1, pi1, pv2);
    k_foldmerge<<<dim3(12, 12, BATCH), 256, 0, stream>>>(refsr, lrsr, rinv, pv1, pi1, pv2, bns,
                                                         org, outT, outS);
}